// Round 12
// baseline (78.769 us; speedup 1.0000x reference)
//
#include <hip/hip_runtime.h>

// IAF chain encoder, fully fused: one block = 32 batch rows, all 4 flow steps
// in-LDS. Degree-sorted hidden permutation makes all three MADE masks
// k-PREFIXES -> skip structurally-zero k-chunks. Round 12:
//  BALANCED mirror pairing (w, 31-w): per-wave weight-stream bytes are EQUAL
//  (r8's adjacent pairing left wave15 with 1.8x avg -> fair-share-BW bound;
//  r9/r10/r11 latency pipelines all null -> delivery-bound, not latency).
//  Hybrid loop: shared prefix [0,ncS) feeds both tiles from one A-read set
//  (8 MFMA/cp); solo tail [ncS,ncB) for the far tile (4 MFMA/cp). Codegen =
//  r8's named-reg dist-1 double buffer (the only scratch-free shape).

typedef _Float16 f16;
typedef __attribute__((ext_vector_type(8))) _Float16 f16x8;
typedef __attribute__((ext_vector_type(4))) float f32x4;

#define NB 8192
#define ND 256
#define NH 512
#define NT 4
#define XSTR 260   // xbuf row stride (floats)

// ws layout (fp16 els), fragment-native [T][tile=32][ks<KSMAX][lane=64][8]
// (fixed tile stride = KSMAX*512 els; chunks >= true nks(tile) are ZEROS)
#define W1F_OFF 0                        // KSMAX=8  : T*32*8*512  = T*NH*ND
#define W2F_OFF (NT*NH*ND)               // KSMAX=16 : T*32*16*512 = T*NH*NH
#define W3F_OFF (W2F_OFF + NT*NH*NH)     // KSMAX=16
#define WS_ELEMS (W3F_OFF + NT*NH*NH)    // 2,621,440 els = 5.24 MB

// Degree-sorted hidden permutation. deg_h[n] = 1 + n%255 over n in [0,512).
//   j<3: deg 1, orig {0,255,510}; 3<=j<6: deg 2, orig {1,256,511};
//   j>=6: deg j>>1, orig = (j&1) ? (j>>1)+254 : (j>>1)-1.
__device__ __forceinline__ int h_orig(int j) {
  if (j < 3) return j == 0 ? 0 : (j == 1 ? 255 : 510);
  if (j < 6) return j == 3 ? 1 : (j == 4 ? 256 : 511);
  int d = j >> 1;
  return (j & 1) ? (d + 254) : (d - 1);
}
__device__ __forceinline__ int h_deg(int j) {
  return (j < 3) ? 1 : (j < 6) ? 2 : (j >> 1);
}

// M1[k][j]: k <= deg(j)-1 ; M2[k][j]: deg(k) <= deg(j) ; M3[k][n]: deg(k) <= n>>1
__global__ void prep_weights(const float* __restrict__ W1,
                             const float* __restrict__ W2,
                             const float* __restrict__ W3,
                             f16* __restrict__ ws)
{
  int idx = blockIdx.x * blockDim.x + threadIdx.x;
  if (idx >= WS_ELEMS) return;
  float v;
  if (idx < W2F_OFF) {
    int t = idx >> 17, r = idx & ((1 << 17) - 1);     // 32*8*512 = 131072
    int e = r & 7, lane = (r >> 3) & 63, ks = (r >> 9) & 7, tile = r >> 12;
    int j = tile * 16 + (lane & 15);                  // sorted hidden col
    int k = ks * 32 + (lane >> 4) * 8 + e;            // raw input row
    v = (k <= h_deg(j) - 1) ? W1[t * (ND * NH) + k * NH + h_orig(j)] : 0.f;
  } else if (idx < W3F_OFF) {
    int q = idx - W2F_OFF;
    int t = q >> 18, r = q & ((1 << 18) - 1);         // 32*16*512 = 262144
    int e = r & 7, lane = (r >> 3) & 63, ks = (r >> 9) & 15, tile = r >> 13;
    int j = tile * 16 + (lane & 15);                  // sorted hidden col
    int k = ks * 32 + (lane >> 4) * 8 + e;            // sorted hidden row
    v = (h_deg(k) <= h_deg(j)) ? W2[t * (NH * NH) + h_orig(k) * NH + h_orig(j)] : 0.f;
  } else {
    int q = idx - W3F_OFF;
    int t = q >> 18, r = q & ((1 << 18) - 1);
    int e = r & 7, lane = (r >> 3) & 63, ks = (r >> 9) & 15, tile = r >> 13;
    int n = tile * 16 + (lane & 15);                  // raw output col
    int k = ks * 32 + (lane >> 4) * 8 + e;            // sorted hidden row
    v = (h_deg(k) <= (n >> 1)) ? W3[t * (NH * 2 * ND) + h_orig(k) * (2 * ND) + n] : 0.f;
  }
  ws[idx] = (f16)v;
}

#define MFMA16 __builtin_amdgcn_mfma_f32_16x16x32_f16

// Mirror-paired hybrid gemm. Tiles S (near, ncS chunks) and B (far, ncB>ncS).
// Shared prefix: one A-read set feeds both B-streams; solo tail: B only.
// All regs named, dist-1 double buffer, wave-uniform trip counts.
template<int SSTRB>
__device__ __forceinline__ void gemm_hybrid(const f16* srcA,
                                            const f16* __restrict__ wtS,
                                            const f16* __restrict__ wtB,
                                            int ncS, int ncB,
                                            int lrow, int lk8,
                                            f32x4 &aS0, f32x4 &aS1,
                                            f32x4 &aB0, f32x4 &aB1)
{
  const f32x4 z = {0.f, 0.f, 0.f, 0.f};
  aS0 = z; aS1 = z; aB0 = z; aB1 = z;
  const int r1 = 16 + lrow;
  const int swz0 = (lrow & 7) << 4;
  const int swz1 = (r1 & 7) << 4;

  // ---- shared prefix: chunks [0, ncS), both tiles
  f16x8 cS0 = *(const f16x8*)(wtS);
  f16x8 cS1 = *(const f16x8*)(wtS + 512);
  f16x8 cB0 = *(const f16x8*)(wtB);
  f16x8 cB1 = *(const f16x8*)(wtB + 512);
  for (int c = 0; ; ++c) {
    f16x8 nS0, nS1, nB0, nB1;
    const bool more = (c + 1 < ncS);               // wave-uniform
    if (more) {
      const f16* pS = wtS + (c + 1) * 1024;
      const f16* pB = wtB + (c + 1) * 1024;
      nS0 = *(const f16x8*)(pS);
      nS1 = *(const f16x8*)(pS + 512);
      nB0 = *(const f16x8*)(pB);
      nB1 = *(const f16x8*)(pB + 512);
    }
    #pragma unroll
    for (int u = 0; u < 2; ++u) {
      int kb = 128 * c + u * 64 + lk8 * 16;
      f16x8 a0 = *(const f16x8*)((const char*)srcA + ((lrow * SSTRB + kb) ^ swz0));
      f16x8 a1 = *(const f16x8*)((const char*)srcA + ((r1 * SSTRB + kb) ^ swz1));
      f16x8 bS = u ? cS1 : cS0;
      f16x8 bB = u ? cB1 : cB0;
      aS0 = MFMA16(a0, bS, aS0, 0, 0, 0);
      aS1 = MFMA16(a1, bS, aS1, 0, 0, 0);
      aB0 = MFMA16(a0, bB, aB0, 0, 0, 0);
      aB1 = MFMA16(a1, bB, aB1, 0, 0, 0);
    }
    if (!more) break;
    cS0 = nS0; cS1 = nS1; cB0 = nB0; cB1 = nB1;
  }

  // ---- solo tail: chunks [ncS, ncB), far tile only
  if (ncS < ncB) {
    f16x8 dB0 = *(const f16x8*)(wtB + ncS * 1024);
    f16x8 dB1 = *(const f16x8*)(wtB + ncS * 1024 + 512);
    for (int c = ncS; ; ++c) {
      f16x8 nB0, nB1;
      const bool more = (c + 1 < ncB);             // wave-uniform
      if (more) {
        const f16* pB = wtB + (c + 1) * 1024;
        nB0 = *(const f16x8*)(pB);
        nB1 = *(const f16x8*)(pB + 512);
      }
      #pragma unroll
      for (int u = 0; u < 2; ++u) {
        int kb = 128 * c + u * 64 + lk8 * 16;
        f16x8 a0 = *(const f16x8*)((const char*)srcA + ((lrow * SSTRB + kb) ^ swz0));
        f16x8 a1 = *(const f16x8*)((const char*)srcA + ((r1 * SSTRB + kb) ^ swz1));
        f16x8 bB = u ? dB1 : dB0;
        aB0 = MFMA16(a0, bB, aB0, 0, 0, 0);
        aB1 = MFMA16(a1, bB, aB1, 0, 0, 0);
      }
      if (!more) break;
      dB0 = nB0; dB1 = nB1;
    }
  }
}

// relu(acc + bias) -> fp16 LDS tile [32][512] (sorted cols), swizzled,
// row stride 1024B. Pair-stores via shfl_xor -> all-lane ds_write_b32.
__device__ __forceinline__ void epi_relu_tile(f32x4 a0, f32x4 a1,
                                              const float* __restrict__ bias_t,
                                              f16* dst, int np, int lrow, int lk8)
{
  const bool ev = (lrow & 1) == 0;
  int n = np + lrow;
  float bv = bias_t[h_orig(n)];
  #pragma unroll
  for (int j = 0; j < 4; ++j) {
    float v0 = fmaxf(a0[j] + bv, 0.f);
    float v1 = fmaxf(a1[j] + bv, 0.f);
    float p0 = __shfl_xor(v0, 1);
    float p1 = __shfl_xor(v1, 1);
    float lo = ev ? v0 : p1;
    float hi = ev ? p0 : v1;
    int m = (ev ? 0 : 16) + lk8 * 4 + j;
    int nw = n & ~1;
    unsigned int w = (unsigned int)__builtin_bit_cast(unsigned short, (f16)lo)
                   | ((unsigned int)__builtin_bit_cast(unsigned short, (f16)hi) << 16);
    int off = m * 1024 + nw * 2;
    *(unsigned int*)((char*)dst + (off ^ ((m & 7) << 4))) = w;
  }
}

__global__ __launch_bounds__(1024, 4) void iaf_main(
    const float* __restrict__ mean, const float* __restrict__ logv,
    const float* __restrict__ eps,
    const float* __restrict__ b1, const float* __restrict__ b2,
    const float* __restrict__ b3,
    const f16* __restrict__ ws, float* __restrict__ out)
{
  __shared__ float xbuf[32][XSTR];                // 33.3 KB fp32 master x
  __shared__ __align__(16) f16 buf0[32 * 512];    // 32 KB (A1 uses 16 KB)
  __shared__ __align__(16) f16 buf1[32 * 512];    // 32 KB

  const int tid = threadIdx.x;
  const int wid = tid >> 6;
  const int lane = tid & 63;
  const int lrow = lane & 15;    // MFMA row (A) / col (B,C)
  const int lk8 = lane >> 4;     // MFMA k-chunk / row-group
  const int row0 = blockIdx.x * 32;

  // mirror pairing: wave w owns tiles {w, 31-w}; per-wave chunk totals and
  // BYTES are equal for every wave (W1: 5 cp, W2/W3: 9 cp, 18KB).
  const int tS = wid, tB = 31 - wid;
  const int npS = tS * 16, npB = tB * 16;
  const int nc1S = tS / 8 + 1, nc1B = tB / 8 + 1;     // W1 chunk-pairs
  const int nc23S = tS / 4 + 1, nc23B = tB / 4 + 1;   // W2/W3 chunk-pairs

  // x0 = mean + exp(0.5*log_var)*eps
  {
    int m = tid >> 5;
    int c0 = (tid & 31) * 8;
    const int g = (row0 + m) * ND + c0;
    #pragma unroll
    for (int i = 0; i < 8; i += 4) {
      f32x4 mu = *(const f32x4*)(mean + g + i);
      f32x4 lv = *(const f32x4*)(logv + g + i);
      f32x4 ep = *(const f32x4*)(eps + g + i);
      f32x4 x;
      #pragma unroll
      for (int q = 0; q < 4; ++q) x[q] = mu[q] + __expf(0.5f * lv[q]) * ep[q];
      *(f32x4*)(&xbuf[m][c0 + i]) = x;
    }
  }
  __syncthreads();

  for (int t = NT - 1; t >= 0; --t) {
    // A1[m][k] = fp16(x[m][255-k]) (reversal folded in), stride 512B, swizzled
    {
      int m = tid >> 5;
      int k0 = (tid & 31) * 8;
      f32x4 lo = *(const f32x4*)(&xbuf[m][248 - k0]);
      f32x4 hi = *(const f32x4*)(&xbuf[m][252 - k0]);
      f16x8 pk;
      pk[0] = (f16)hi[3]; pk[1] = (f16)hi[2]; pk[2] = (f16)hi[1]; pk[3] = (f16)hi[0];
      pk[4] = (f16)lo[3]; pk[5] = (f16)lo[2]; pk[6] = (f16)lo[1]; pk[7] = (f16)lo[0];
      int off = m * 512 + k0 * 2;
      *(f16x8*)((char*)buf0 + (off ^ ((m & 7) << 4))) = pk;
    }
    __syncthreads();

    f32x4 aS0, aS1, aB0, aB1;

    // h1 = relu(x_rev @ W1m + b1)   (sorted cols)
    {
      const f16* w1b = ws + W1F_OFF + t * (NH * ND);
      gemm_hybrid<512>(buf0,
                       w1b + tS * 4096 + lane * 8,
                       w1b + tB * 4096 + lane * 8,
                       nc1S, nc1B, lrow, lk8, aS0, aS1, aB0, aB1);
      epi_relu_tile(aS0, aS1, b1 + t * NH, buf1, npS, lrow, lk8);
      epi_relu_tile(aB0, aB1, b1 + t * NH, buf1, npB, lrow, lk8);
    }
    __syncthreads();

    // h2 = relu(h1 @ W2m + b2)   (sorted rows+cols)
    {
      const f16* w2b = ws + W2F_OFF + t * (NH * NH);
      gemm_hybrid<1024>(buf1,
                        w2b + tS * 8192 + lane * 8,
                        w2b + tB * 8192 + lane * 8,
                        nc23S, nc23B, lrow, lk8, aS0, aS1, aB0, aB1);
      epi_relu_tile(aS0, aS1, b2 + t * NH, buf0, npS, lrow, lk8);
      epi_relu_tile(aB0, aB1, b2 + t * NH, buf0, npB, lrow, lk8);
    }
    __syncthreads();

    // out = h2 @ W3m + b3 ;  shift = out[:,2d], log_var = out[:,2d+1]
    {
      const f16* w3b = ws + W3F_OFF + t * (NH * NH);
      gemm_hybrid<1024>(buf0,
                        w3b + tS * 8192 + lane * 8,
                        w3b + tB * 8192 + lane * 8,
                        nc23S, nc23B, lrow, lk8, aS0, aS1, aB0, aB1);

      const bool ev = (lrow & 1) == 0;
      const float* b3t = b3 + t * (2 * ND);
      float xnS[2][4], xnB[2][4];
      #pragma unroll
      for (int pt = 0; pt < 2; ++pt) {
        f32x4 o_0 = pt ? aB0 : aS0;
        f32x4 o_1 = pt ? aB1 : aS1;
        float (*xn)[4] = pt ? xnB : xnS;
        int n = (pt ? npB : npS) + lrow;
        float bv = b3t[n];
        #pragma unroll
        for (int j = 0; j < 4; ++j) {
          float o0 = o_0[j] + bv;
          float o1 = o_1[j] + bv;
          float po0 = __shfl_xor(o0, 1);   // partner column (n^1) value
          float po1 = __shfl_xor(o1, 1);
          if (ev) {                         // even col: o=shift, po=pre-tanh lv
            int d = n >> 1;
            float xc0 = xbuf[lk8 * 4 + j][255 - d];
            float e0 = __expf(2.f * po0);
            float t0 = 1.f - 2.f / (e0 + 1.f);          // tanh(po0)
            xn[0][j] = (xc0 - o0) * __expf(-t0);
            float xc1 = xbuf[16 + lk8 * 4 + j][255 - d];
            float e1 = __expf(2.f * po1);
            float t1 = 1.f - 2.f / (e1 + 1.f);
            xn[1][j] = (xc1 - o1) * __expf(-t1);
          }
        }
      }
      __syncthreads();                      // all xbuf reads done
      if (ev) {
        int dS = (npS + lrow) >> 1;
        int dB = (npB + lrow) >> 1;
        #pragma unroll
        for (int j = 0; j < 4; ++j) {
          xbuf[lk8 * 4 + j][dS]      = xnS[0][j];
          xbuf[16 + lk8 * 4 + j][dS] = xnS[1][j];
          xbuf[lk8 * 4 + j][dB]      = xnB[0][j];
          xbuf[16 + lk8 * 4 + j][dB] = xnB[1][j];
        }
      }
      __syncthreads();
    }
  }

  // store final x (fp32)
  {
    int m = tid >> 5;
    int c0 = (tid & 31) * 8;
    float* op = out + (row0 + m) * ND + c0;
    #pragma unroll
    for (int i = 0; i < 8; i += 4)
      *(f32x4*)(op + i) = *(const f32x4*)(&xbuf[m][c0 + i]);
  }
}

extern "C" void kernel_launch(void* const* d_in, const int* in_sizes, int n_in,
                              void* d_out, int out_size, void* d_ws, size_t ws_size,
                              hipStream_t stream) {
  const float* mean = (const float*)d_in[0];
  const float* logv = (const float*)d_in[1];
  const float* eps  = (const float*)d_in[2];
  const float* W1   = (const float*)d_in[3];
  const float* b1   = (const float*)d_in[4];
  const float* W2   = (const float*)d_in[5];
  const float* b2   = (const float*)d_in[6];
  const float* W3   = (const float*)d_in[7];
  const float* b3   = (const float*)d_in[8];
  f16* ws = (f16*)d_ws;   // needs 5.25 MB

  prep_weights<<<(WS_ELEMS + 255) / 256, 256, 0, stream>>>(W1, W2, W3, ws);
  iaf_main<<<NB / 32, 1024, 0, stream>>>(mean, logv, eps, b1, b2, b3, ws,
                                         (float*)d_out);
}